// Round 16
// baseline (300.468 us; speedup 1.0000x reference)
//
#include <hip/hip_runtime.h>
#include <hip/hip_bf16.h>
#include <string.h>

#define NL 32
#define HID 64

// Piecewise-linear f32 cell table over z1 in [-16, 16], 512 cells (1/16).
// ReLU MLP on a scalar is exactly piecewise-linear; lerp + edge extrapolation
// validated rounds 1-14 (absmax 0.031 with f32 lerp, threshold 0.209).
// FUSED single kernel: build (256 blocks x 64 nodes each) -> device-scope
// semaphore grid-sync -> flow. Eliminates the build launch + inter-kernel
// drain (~10 us of fixed overhead identified in r12-r14 plateau).
#define NCELLS 512
#define SCALE  16.0f
#define OFFSET 256.0f

#define GRID 256                     // 1 block/CU (capacity 2 -> no deadlock)
#define TPB  1024                    // 16 waves
#define RPT  8
#define ROWS_PER_BLOCK (TPB * RPT)   // 8192; 256*8192 = 2,097,152 rows exact

#define NODES_BYTES ((size_t)NL * NCELLS * sizeof(float2))   // 128 KB
#define WS_NEED (NODES_BYTES + 64)

// ---------------- helpers ---------------------------------------------------
__device__ __forceinline__ float2 nt_load_f2(const float* p) {
    unsigned long long raw =
        __builtin_nontemporal_load((const unsigned long long*)p);
    float2 v;
    memcpy(&v, &raw, 8);
    return v;
}
__device__ __forceinline__ void nt_store_f2(float* p, float2 v) {
    unsigned long long raw;
    memcpy(&raw, &v, 8);
    __builtin_nontemporal_store(raw, (unsigned long long*)p);
}

// ---------------- fused kernel ----------------------------------------------
// launch_bounds(1024, 8): 8 waves/EU -> VGPR <= 64 -> 2 blocks/CU capacity.
// Grid is 256 = 1 block/CU expected; capacity 2 gives deadlock margin for the
// semaphore even if the dispatcher double-books a CU.
__global__ __launch_bounds__(TPB, 8) void fused_flow_kernel(
    const float* __restrict__ x,
    const float* __restrict__ W1,
    const float* __restrict__ b1,
    const float* __restrict__ W2,
    const float* __restrict__ b2,
    const float* __restrict__ W3,
    const float* __restrict__ b3,
    float2* __restrict__ nodes,        // d_ws, NL*NCELLS float2
    unsigned int* __restrict__ sem,    // d_ws + NODES_BYTES (memset 0 per call)
    float* __restrict__ out,
    int nrows)
{
    // LDS arena: build uses part[16][8][64] f32 (32 KB) + part2[8][64] f2 (4 KB);
    // flow phase reuses it as buf[2][512] float4 (16 KB).
    __shared__ char smem[36864];
    float*  part  = (float*)smem;                 // [wave][jj][lane]
    float2* part2 = (float2*)(smem + 32768);      // [wave8][lane]

    const int tid  = threadIdx.x;
    const int lane = tid & 63;
    const int wave = tid >> 6;                    // 0..15

    // ================= phase 1: build 64 nodes of one layer =================
    {
        const int l     = blockIdx.x & 31;
        const int chunk = blockIdx.x >> 5;        // 0..7
        const int node  = chunk * 64 + lane;      // 0..511
        const float av  = -16.0f + (float)node * (1.0f / 16.0f);  // exact fp32

        const float* __restrict__ w1 = W1 + l * HID;
        const float* __restrict__ c1 = b1 + l * HID;
        const float* __restrict__ w2 = W2 + l * HID * HID;
        const float* __restrict__ c2 = b2 + l * HID;
        const float* __restrict__ w3 = W3 + l * 2 * HID;
        const float* __restrict__ c3 = b3 + l * 2;

        // wave w: j-group jg = w&7 (8 rows), k-half kh = w>>3 (32 of 64 k).
        // readfirstlane keeps weight addressing wave-uniform -> s_load
        // broadcast (round-10 lesson: lane-varying rows -> per-lane vmem).
        const int j0 = __builtin_amdgcn_readfirstlane((wave & 7) * 8);
        const int k0 = __builtin_amdgcn_readfirstlane((wave >> 3) * 32);

        float h1[32];                 // only our k-half: fits VGPR<=64 budget
        #pragma unroll
        for (int k = 0; k < 32; ++k) {
            float v = fmaxf(fmaf(av, w1[k0 + k], c1[k0 + k]), 0.0f);
            asm volatile("" : "+v"(v));   // pin; block rematerialization
            h1[k] = v;
        }

        #pragma unroll
        for (int jj = 0; jj < 8; ++jj) {
            const float* __restrict__ w2row = w2 + (j0 + jj) * HID + k0;
            float acc0 = 0.0f, acc1 = 0.0f;
            #pragma unroll
            for (int k = 0; k < 32; k += 2) {
                acc0 = fmaf(h1[k],     w2row[k],     acc0);
                acc1 = fmaf(h1[k + 1], w2row[k + 1], acc1);
            }
            // layout [wave][jj][lane]: stride-64 writes, conflict-free
            part[(wave * 8 + jj) * 64 + lane] = acc0 + acc1;
        }
        __syncthreads();

        if (wave < 8) {   // combine k-halves BEFORE relu, fold w3
            float o0 = 0.0f, o1 = 0.0f;
            #pragma unroll
            for (int jj = 0; jj < 8; ++jj) {
                const int j = j0 + jj;                     // j0 = wave*8 here
                float d = part[(wave * 8 + jj) * 64 + lane]
                        + part[((wave + 8) * 8 + jj) * 64 + lane];
                float h = fmaxf(d + c2[j], 0.0f);
                o0 = fmaf(h, w3[j], o0);
                o1 = fmaf(h, w3[HID + j], o1);
            }
            part2[wave * 64 + lane] = make_float2(o0, o1);
        }
        __syncthreads();

        if (tid < 64) {
            float s0 = c3[0], s1 = c3[1];
            #pragma unroll
            for (int w = 0; w < 8; ++w) {
                float2 p = part2[w * 64 + tid];
                s0 += p.x;
                s1 += p.y;
            }
            nodes[l * NCELLS + chunk * 64 + tid] = make_float2(s0, expf(s1));
            __threadfence();   // publish device-wide before the signal
        }
        __syncthreads();
    }

    // ================= grid semaphore (all 256 blocks) ======================
    if (tid == 0) {
        __hip_atomic_fetch_add(sem, 1u, __ATOMIC_RELEASE,
                               __HIP_MEMORY_SCOPE_AGENT);
        while (__hip_atomic_load(sem, __ATOMIC_ACQUIRE,
                                 __HIP_MEMORY_SCOPE_AGENT) < (unsigned)gridDim.x) {
            __builtin_amdgcn_s_sleep(2);
        }
    }
    __syncthreads();
    __threadfence();   // acquire side: no stale node reads

    // ================= phase 2: flow (r12-style f32 LDS table) ==============
    float4 (*buf)[NCELLS] = (float4(*)[NCELLS])smem;   // reuse arena, 16 KB

    const size_t rbase = (size_t)blockIdx.x * ROWS_PER_BLOCK;
    float a[RPT], b[RPT];
    #pragma unroll
    for (int i = 0; i < RPT; ++i) {
        size_t r = rbase + (size_t)i * TPB + tid;
        float2 z = (r < (size_t)nrows) ? nt_load_f2(x + 2 * r)
                                       : make_float2(0.f, 0.f);
        a[i] = z.x;
        b[i] = z.y;
    }

    // cell t from nodes t,t+1; cell 511 = linear extension of cell 510
    const int t  = tid;
    const int tm = (t < NCELLS - 1) ? t : NCELLS - 2;
    const int tp = (t < NCELLS - 1) ? t + 1 : NCELLS - 1;

    if (t < NCELLS) {
        float2 A = nodes[tm], B = nodes[tp];
        float2 base = (t < NCELLS - 1) ? A : B;
        buf[0][t] = make_float4(base.x, base.y, B.x - A.x, B.y - A.y);
    }
    __syncthreads();

    int cur = 0;
    for (int l = 0; l < NL; ++l) {
        // prefetch next layer's nodes; pin so loads can't be sunk (r7 lesson)
        float2 A, B;
        if (l + 1 < NL && t < NCELLS) {
            const float2* __restrict__ ns = nodes + (l + 1) * NCELLS;
            A = ns[tm];
            B = ns[tp];
            asm volatile("" : "+v"(A.x), "+v"(A.y), "+v"(B.x), "+v"(B.y));
        }

        // gather-compute from buf[cur] (f32 lerp, 3 fmaf -- VALU-lean)
        #pragma unroll
        for (int i = 0; i < RPT; ++i) {
            float tt = fmaf(a[i], SCALE, OFFSET);
            int idx = (int)tt;
            idx = idx < 0 ? 0 : (idx > NCELLS - 1 ? NCELLS - 1 : idx);
            float f = tt - (float)idx;           // out-of-range -> extrapolate
            float4 nd = buf[cur][idx];
            float sh = fmaf(f, nd.z, nd.x);
            float sc = fmaf(f, nd.w, nd.y);
            float nb = fmaf(b[i], sc, sh);
            b[i] = a[i];
            a[i] = nb;
        }

        if (l + 1 < NL && t < NCELLS) {
            float2 base = (t < NCELLS - 1) ? A : B;
            buf[cur ^ 1][t] = make_float4(base.x, base.y, B.x - A.x, B.y - A.y);
        }
        __syncthreads();
        cur ^= 1;
    }

    #pragma unroll
    for (int i = 0; i < RPT; ++i) {
        size_t r = rbase + (size_t)i * TPB + tid;
        if (r < (size_t)nrows)
            nt_store_f2(out + 2 * r, make_float2(a[i], b[i]));
    }
}

// ---------------- fallback: direct fp32 (ws too small) ---------------------
__global__ __launch_bounds__(256, 2) void flow_fp32_kernel(
    const float* __restrict__ x,
    const float* __restrict__ W1,
    const float* __restrict__ b1,
    const float* __restrict__ W2,
    const float* __restrict__ b2,
    const float* __restrict__ W3,
    const float* __restrict__ b3,
    float* __restrict__ out,
    int nrows)
{
    int row = blockIdx.x * blockDim.x + threadIdx.x;
    if (row >= nrows) return;

    float2 z = reinterpret_cast<const float2*>(x)[row];
    float a = z.x;
    float b = z.y;

    for (int l = 0; l < NL; ++l) {
        const float* __restrict__ w1 = W1 + l * HID;
        const float* __restrict__ c1 = b1 + l * HID;
        const float* __restrict__ w2 = W2 + l * HID * HID;
        const float* __restrict__ c2 = b2 + l * HID;
        const float* __restrict__ w3 = W3 + l * 2 * HID;
        const float* __restrict__ c3 = b3 + l * 2;

        float h1[HID];
        #pragma unroll
        for (int k = 0; k < HID; ++k) {
            float v = fmaxf(fmaf(a, w1[k], c1[k]), 0.0f);
            asm volatile("" : "+v"(v));
            h1[k] = v;
        }

        float o0 = c3[0];
        float o1 = c3[1];

        #pragma unroll 2
        for (int j = 0; j < HID; ++j) {
            const float* __restrict__ w2row = w2 + j * HID;
            float acc0 = c2[j];
            float acc1 = 0.0f;
            #pragma unroll
            for (int k = 0; k < HID; k += 2) {
                acc0 = fmaf(h1[k],     w2row[k],     acc0);
                acc1 = fmaf(h1[k + 1], w2row[k + 1], acc1);
            }
            float h = fmaxf(acc0 + acc1, 0.0f);
            o0 = fmaf(h, w3[j], o0);
            o1 = fmaf(h, w3[HID + j], o1);
        }

        float nb = fmaf(b, __expf(o1), o0);
        b = a;
        a = nb;
    }

    reinterpret_cast<float2*>(out)[row] = make_float2(a, b);
}

extern "C" void kernel_launch(void* const* d_in, const int* in_sizes, int n_in,
                              void* d_out, int out_size, void* d_ws, size_t ws_size,
                              hipStream_t stream)
{
    const float* x  = (const float*)d_in[0];
    const float* W1 = (const float*)d_in[1];
    const float* b1 = (const float*)d_in[2];
    const float* W2 = (const float*)d_in[3];
    const float* b2 = (const float*)d_in[4];
    const float* W3 = (const float*)d_in[5];
    const float* b3 = (const float*)d_in[6];
    float* out = (float*)d_out;

    int nrows = in_sizes[0] / 2;

    if (ws_size >= WS_NEED) {
        float2* nodes = (float2*)d_ws;
        unsigned int* sem = (unsigned int*)((char*)d_ws + NODES_BYTES);
        // reset the semaphore every call (deterministic; capture-legal)
        hipMemsetAsync(sem, 0, sizeof(unsigned int), stream);
        fused_flow_kernel<<<GRID, TPB, 0, stream>>>(
            x, W1, b1, W2, b2, W3, b3, nodes, sem, out, nrows);
    } else {
        int grid = (nrows + 255) / 256;
        flow_fp32_kernel<<<grid, 256, 0, stream>>>(x, W1, b1, W2, b2, W3, b3, out, nrows);
    }
}

// Round 17
// 107.142 us; speedup vs baseline: 2.8044x; 2.8044x over previous
//
#include <hip/hip_runtime.h>
#include <hip/hip_bf16.h>
#include <string.h>

#define NL 32
#define HID 64

// Piecewise-linear f32 cell table over z1 in [-16, 16], 512 cells (1/16).
// ReLU MLP on a scalar is exactly piecewise-linear; lerp + edge extrapolation
// validated rounds 1-15 (absmax 0.031, threshold 0.209).
// FUSED single kernel: build -> device semaphore grid-sync -> flow.
// Round-15 lesson: launch_bounds(1024,8) capped VGPR at 64 -> compiler chose
// 32 and spilled (WRITE_SIZE 451 MB of scratch, 305 us). This version:
// TPB=512, launch_bounds(512,4) -> VGPR <= 128, no spill.
#define NCELLS 512
#define SCALE  16.0f
#define OFFSET 256.0f

#define GRID 256                     // 1 block/CU (capacity 2 -> no deadlock)
#define TPB  512                     // 8 waves
#define RPT  16
#define ROWS_PER_BLOCK (TPB * RPT)   // 8192; 256*8192 = 2,097,152 rows exact

#define NODES_BYTES ((size_t)NL * NCELLS * sizeof(float2))   // 128 KB
#define WS_NEED (NODES_BYTES + 64)

// ---------------- helpers ---------------------------------------------------
__device__ __forceinline__ float2 nt_load_f2(const float* p) {
    unsigned long long raw =
        __builtin_nontemporal_load((const unsigned long long*)p);
    float2 v;
    memcpy(&v, &raw, 8);
    return v;
}
__device__ __forceinline__ void nt_store_f2(float* p, float2 v) {
    unsigned long long raw;
    memcpy(&raw, &v, 8);
    __builtin_nontemporal_store(raw, (unsigned long long*)p);
}

// ---------------- fused kernel ----------------------------------------------
__global__ __launch_bounds__(TPB, 4) void fused_flow_kernel(
    const float* __restrict__ x,
    const float* __restrict__ W1,
    const float* __restrict__ b1,
    const float* __restrict__ W2,
    const float* __restrict__ b2,
    const float* __restrict__ W3,
    const float* __restrict__ b3,
    float2* __restrict__ nodes,        // d_ws, NL*NCELLS float2
    unsigned int* __restrict__ sem,    // d_ws + NODES_BYTES (memset 0 per call)
    float* __restrict__ out,
    int nrows)
{
    // LDS arena: flow uses buf[2][512] float4 (16 KB); build reuses the
    // first 4 KB as part2[8][64] float2.
    __shared__ float4 buf[2][NCELLS];
    float2* part2 = (float2*)buf;

    const int tid  = threadIdx.x;
    const int lane = tid & 63;
    const int wave = tid >> 6;                    // 0..7

    // ================= phase 1: build 64 nodes of one layer =================
    // Block b: layer = b&31, node-chunk = b>>5. Lane = node, wave w owns
    // j in [8w, 8w+8) with FULL k (h1[64] fits the 128-VGPR budget).
    // readfirstlane keeps weight rows wave-uniform -> s_load broadcast
    // (round-10 lesson: lane-varying rows demote to per-lane vmem loads).
    {
        const int l     = blockIdx.x & 31;
        const int chunk = blockIdx.x >> 5;        // 0..7
        const int node  = chunk * 64 + lane;      // 0..511
        const float av  = -16.0f + (float)node * (1.0f / 16.0f);  // exact fp32

        const float* __restrict__ w1 = W1 + l * HID;
        const float* __restrict__ c1 = b1 + l * HID;
        const float* __restrict__ w2 = W2 + l * HID * HID;
        const float* __restrict__ c2 = b2 + l * HID;
        const float* __restrict__ w3 = W3 + l * 2 * HID;
        const float* __restrict__ c3 = b3 + l * 2;

        float h1[HID];
        #pragma unroll
        for (int k = 0; k < HID; ++k) {
            float v = fmaxf(fmaf(av, w1[k], c1[k]), 0.0f);
            asm volatile("" : "+v"(v));   // pin; block rematerialization
            h1[k] = v;
        }

        const int j0 = __builtin_amdgcn_readfirstlane(wave * 8);

        float o0 = 0.0f, o1 = 0.0f;
        #pragma unroll
        for (int jj = 0; jj < 8; ++jj) {
            const int j = j0 + jj;
            const float* __restrict__ w2row = w2 + j * HID;
            float acc0 = c2[j];
            float acc1 = 0.0f;
            #pragma unroll
            for (int k = 0; k < HID; k += 2) {
                acc0 = fmaf(h1[k],     w2row[k],     acc0);
                acc1 = fmaf(h1[k + 1], w2row[k + 1], acc1);
            }
            float h = fmaxf(acc0 + acc1, 0.0f);
            o0 = fmaf(h, w3[j], o0);
            o1 = fmaf(h, w3[HID + j], o1);
        }
        part2[wave * 64 + lane] = make_float2(o0, o1);
        __syncthreads();

        if (tid < 64) {
            float s0 = c3[0], s1 = c3[1];
            #pragma unroll
            for (int w = 0; w < 8; ++w) {
                float2 p = part2[w * 64 + tid];
                s0 += p.x;
                s1 += p.y;
            }
            nodes[l * NCELLS + chunk * 64 + tid] = make_float2(s0, expf(s1));
            __threadfence();   // publish device-wide before the signal
        }
        __syncthreads();
    }

    // ================= grid semaphore (all 256 blocks) ======================
    if (tid == 0) {
        __hip_atomic_fetch_add(sem, 1u, __ATOMIC_RELEASE,
                               __HIP_MEMORY_SCOPE_AGENT);
        while (__hip_atomic_load(sem, __ATOMIC_ACQUIRE,
                                 __HIP_MEMORY_SCOPE_AGENT) < (unsigned)gridDim.x) {
            __builtin_amdgcn_s_sleep(2);
        }
    }
    __syncthreads();
    __threadfence();   // acquire side: no stale node reads

    // ================= phase 2: flow (f32 LDS cell table, dbuf) =============
    const size_t rbase = (size_t)blockIdx.x * ROWS_PER_BLOCK;
    float a[RPT], b[RPT];
    #pragma unroll
    for (int i = 0; i < RPT; ++i) {
        size_t r = rbase + (size_t)i * TPB + tid;
        float2 z = (r < (size_t)nrows) ? nt_load_f2(x + 2 * r)
                                       : make_float2(0.f, 0.f);
        a[i] = z.x;
        b[i] = z.y;
    }

    // cell t from nodes t,t+1; cell 511 = linear extension of cell 510
    const int t  = tid;
    const int tm = (t < NCELLS - 1) ? t : NCELLS - 2;
    const int tp = (t < NCELLS - 1) ? t + 1 : NCELLS - 1;

    {
        float2 A = nodes[tm], B = nodes[tp];
        float2 base = (t < NCELLS - 1) ? A : B;
        buf[0][t] = make_float4(base.x, base.y, B.x - A.x, B.y - A.y);
    }
    __syncthreads();

    int cur = 0;
    for (int l = 0; l < NL; ++l) {
        // prefetch next layer's nodes; pin so loads can't be sunk (r7 lesson)
        float2 A, B;
        if (l + 1 < NL) {
            const float2* __restrict__ ns = nodes + (l + 1) * NCELLS;
            A = ns[tm];
            B = ns[tp];
            asm volatile("" : "+v"(A.x), "+v"(A.y), "+v"(B.x), "+v"(B.y));
        }

        // gather-compute from buf[cur] (f32 lerp, 3 fmaf -- VALU-lean)
        #pragma unroll
        for (int i = 0; i < RPT; ++i) {
            float tt = fmaf(a[i], SCALE, OFFSET);
            int idx = (int)tt;
            idx = idx < 0 ? 0 : (idx > NCELLS - 1 ? NCELLS - 1 : idx);
            float f = tt - (float)idx;           // out-of-range -> extrapolate
            float4 nd = buf[cur][idx];
            float sh = fmaf(f, nd.z, nd.x);
            float sc = fmaf(f, nd.w, nd.y);
            float nb = fmaf(b[i], sc, sh);
            b[i] = a[i];
            a[i] = nb;
        }

        if (l + 1 < NL) {
            float2 base = (t < NCELLS - 1) ? A : B;
            buf[cur ^ 1][t] = make_float4(base.x, base.y, B.x - A.x, B.y - A.y);
        }
        __syncthreads();
        cur ^= 1;
    }

    #pragma unroll
    for (int i = 0; i < RPT; ++i) {
        size_t r = rbase + (size_t)i * TPB + tid;
        if (r < (size_t)nrows)
            nt_store_f2(out + 2 * r, make_float2(a[i], b[i]));
    }
}

// ---------------- fallback: direct fp32 (ws too small) ---------------------
__global__ __launch_bounds__(256, 2) void flow_fp32_kernel(
    const float* __restrict__ x,
    const float* __restrict__ W1,
    const float* __restrict__ b1,
    const float* __restrict__ W2,
    const float* __restrict__ b2,
    const float* __restrict__ W3,
    const float* __restrict__ b3,
    float* __restrict__ out,
    int nrows)
{
    int row = blockIdx.x * blockDim.x + threadIdx.x;
    if (row >= nrows) return;

    float2 z = reinterpret_cast<const float2*>(x)[row];
    float a = z.x;
    float b = z.y;

    for (int l = 0; l < NL; ++l) {
        const float* __restrict__ w1 = W1 + l * HID;
        const float* __restrict__ c1 = b1 + l * HID;
        const float* __restrict__ w2 = W2 + l * HID * HID;
        const float* __restrict__ c2 = b2 + l * HID;
        const float* __restrict__ w3 = W3 + l * 2 * HID;
        const float* __restrict__ c3 = b3 + l * 2;

        float h1[HID];
        #pragma unroll
        for (int k = 0; k < HID; ++k) {
            float v = fmaxf(fmaf(a, w1[k], c1[k]), 0.0f);
            asm volatile("" : "+v"(v));
            h1[k] = v;
        }

        float o0 = c3[0];
        float o1 = c3[1];

        #pragma unroll 2
        for (int j = 0; j < HID; ++j) {
            const float* __restrict__ w2row = w2 + j * HID;
            float acc0 = c2[j];
            float acc1 = 0.0f;
            #pragma unroll
            for (int k = 0; k < HID; k += 2) {
                acc0 = fmaf(h1[k],     w2row[k],     acc0);
                acc1 = fmaf(h1[k + 1], w2row[k + 1], acc1);
            }
            float h = fmaxf(acc0 + acc1, 0.0f);
            o0 = fmaf(h, w3[j], o0);
            o1 = fmaf(h, w3[HID + j], o1);
        }

        float nb = fmaf(b, __expf(o1), o0);
        b = a;
        a = nb;
    }

    reinterpret_cast<float2*>(out)[row] = make_float2(a, b);
}

extern "C" void kernel_launch(void* const* d_in, const int* in_sizes, int n_in,
                              void* d_out, int out_size, void* d_ws, size_t ws_size,
                              hipStream_t stream)
{
    const float* x  = (const float*)d_in[0];
    const float* W1 = (const float*)d_in[1];
    const float* b1 = (const float*)d_in[2];
    const float* W2 = (const float*)d_in[3];
    const float* b2 = (const float*)d_in[4];
    const float* W3 = (const float*)d_in[5];
    const float* b3 = (const float*)d_in[6];
    float* out = (float*)d_out;

    int nrows = in_sizes[0] / 2;

    if (ws_size >= WS_NEED) {
        float2* nodes = (float2*)d_ws;
        unsigned int* sem = (unsigned int*)((char*)d_ws + NODES_BYTES);
        // reset the semaphore every call (deterministic; capture-legal)
        hipMemsetAsync(sem, 0, sizeof(unsigned int), stream);
        fused_flow_kernel<<<GRID, TPB, 0, stream>>>(
            x, W1, b1, W2, b2, W3, b3, nodes, sem, out, nrows);
    } else {
        int grid = (nrows + 255) / 256;
        flow_fp32_kernel<<<grid, 256, 0, stream>>>(x, W1, b1, W2, b2, W3, b3, out, nrows);
    }
}

// Round 18
// 42.543 us; speedup vs baseline: 7.0628x; 2.5185x over previous
//
#include <hip/hip_runtime.h>
#include <hip/hip_bf16.h>
#include <string.h>

#define NL 32
#define HID 64

// Piecewise-linear f32 cell table over z1 in [-16, 16], 512 cells (1/16).
// ReLU MLP on a scalar is exactly piecewise-linear; lerp + edge extrapolation
// validated rounds 1-16 (absmax 0.031, threshold 0.209). Cell: float4
// (shift, scale=exp(ls), dshift, dscale), single ds_read_b128 gather, f32
// lerp. r12 champion structure: two kernels, DMA dbuf staging, 8 blocks/CU.
// r15/r16 lesson: grid-sync fusion caps occupancy at 8 waves/CU -> 3x slower;
// abandoned. This round: inner-loop VALU trim (fmed3f+trunc index math) and
// float4 row-pair loads/stores.
#define NCELLS 512
#define SCALE  16.0f
#define OFFSET 256.0f
#define TAB_BYTES ((size_t)NL * NCELLS * sizeof(float4))   // 256 KB

#define TPB 256                      // 4 waves per block
#define RPT 4                        // rows per thread -> 2048 blocks = 8/CU
#define ROWS_PER_BLOCK (TPB * RPT)   // 1024
#define CHUNKS (NCELLS / TPB)        // 2 x 16B global_load_lds per thread/layer

#define GN 63                        // cells per build block (64 nodes, 1 overlap)

// ------------- build: wave-level j-split, weights stay wave-uniform --------
// Lane = node (64 nodes/block), wave w handles j in [4w, 4w+4); j0 via
// readfirstlane -> w2row reads stay SGPR broadcast (round-10 lesson: lane-
// level split demotes them to per-lane vector loads, 70 us).
__global__ __launch_bounds__(1024) void build_cells_kernel(
    const float* __restrict__ W1,
    const float* __restrict__ b1,
    const float* __restrict__ W2,
    const float* __restrict__ b2,
    const float* __restrict__ W3,
    const float* __restrict__ b3,
    float4* __restrict__ tab)
{
    const int tid  = threadIdx.x;
    const int lane = tid & 63;
    const int wave = tid >> 6;                 // 0..15
    const int l    = blockIdx.y;
    const int base = blockIdx.x * GN;          // cells [base, base+GN)

    __shared__ float2 part[64][17];            // padded: avoid write conflicts
    __shared__ float2 nodes[64];

    const float* __restrict__ w1 = W1 + l * HID;
    const float* __restrict__ c1 = b1 + l * HID;
    const float* __restrict__ w2 = W2 + l * HID * HID;
    const float* __restrict__ c2 = b2 + l * HID;
    const float* __restrict__ w3 = W3 + l * 2 * HID;
    const float* __restrict__ c3 = b3 + l * 2;

    int node = base + lane;
    if (node > NCELLS) node = NCELLS;          // clamp (duplicate eval, harmless)
    float a = -16.0f + (float)node * (1.0f / 16.0f);   // exact in fp32

    float h1[HID];
    #pragma unroll
    for (int k = 0; k < HID; ++k) {
        float v = fmaxf(fmaf(a, w1[k], c1[k]), 0.0f);
        asm volatile("" : "+v"(v));            // pin in VGPR; block remat
        h1[k] = v;
    }

    // wave-uniform j subset: force the base row index into an SGPR
    const int j0 = __builtin_amdgcn_readfirstlane(wave * 4);

    float o0 = 0.0f;
    float o1 = 0.0f;
    #pragma unroll
    for (int jj = 0; jj < 4; ++jj) {
        const int j = j0 + jj;
        const float* __restrict__ w2row = w2 + j * HID;
        float acc0 = c2[j];
        float acc1 = 0.0f;
        #pragma unroll
        for (int k = 0; k < HID; k += 2) {
            acc0 = fmaf(h1[k],     w2row[k],     acc0);
            acc1 = fmaf(h1[k + 1], w2row[k + 1], acc1);
        }
        float h = fmaxf(acc0 + acc1, 0.0f);
        o0 = fmaf(h, w3[j], o0);
        o1 = fmaf(h, w3[HID + j], o1);
    }
    part[lane][wave] = make_float2(o0, o1);
    __syncthreads();

    if (tid < 64) {
        float s0 = c3[0];
        float s1 = c3[1];
        #pragma unroll
        for (int w = 0; w < 16; ++w) {
            float2 p = part[tid][w];
            s0 += p.x;
            s1 += p.y;
        }
        nodes[tid] = make_float2(s0, expf(s1));   // (shift, scale)
    }
    __syncthreads();

    if (tid < GN && base + tid < NCELLS) {
        float2 v0 = nodes[tid];
        float2 v1 = nodes[tid + 1];
        tab[(size_t)l * NCELLS + base + tid] =
            make_float4(v0.x, v0.y, v1.x - v0.x, v1.y - v0.y);
    }
}

// ---------------- helpers ---------------------------------------------------
__device__ __forceinline__ float4 nt_load_f4(const float* p) {
    float4 v;
    v.x = __builtin_nontemporal_load(p + 0);
    v.y = __builtin_nontemporal_load(p + 1);
    v.z = __builtin_nontemporal_load(p + 2);
    v.w = __builtin_nontemporal_load(p + 3);
    return v;
}
__device__ __forceinline__ void nt_store_f4(float* p, float4 v) {
    __builtin_nontemporal_store(v.x, p + 0);
    __builtin_nontemporal_store(v.y, p + 1);
    __builtin_nontemporal_store(v.z, p + 2);
    __builtin_nontemporal_store(v.w, p + 3);
}

// async global->LDS DMA, 16 B per lane; LDS dest wave-uniform base,
// lane i lands at base + i*16 (linear lane order -> legal here).
__device__ __forceinline__ void gl2lds16(const void* g, void* l) {
    __builtin_amdgcn_global_load_lds(
        (const __attribute__((address_space(1))) void*)g,
        (__attribute__((address_space(3))) void*)l,
        16, 0, 0);
}

// ------- main pass: 512-cell f32 LDS table, DMA staging, 8 blocks/CU -------
// TPB=256 (4 waves), 16 KB LDS/block -> 8 independent blocks per CU: barrier
// drains of one block hide under the gather phases of the other seven.
// Index math: fmed3f + truncf (saves the int-clamp pair + int->float cvt).
// x/out accessed as float4 row pairs (16 B/lane, half the access insts).
__global__ __launch_bounds__(TPB, 8) void flow_lds_kernel(
    const float* __restrict__ x,
    const float4* __restrict__ tabg,
    float* __restrict__ out,
    int nrows)
{
    __shared__ float4 buf[2][NCELLS];   // 2 x 8 KiB

    const int tid = threadIdx.x;
    const int wbase = tid & ~63;        // wave-uniform lane-0 index
    const size_t pbase = (size_t)blockIdx.x * (ROWS_PER_BLOCK / 2);
    const size_t npairs = (size_t)(nrows >> 1);

    float a[RPT], b[RPT];
    #pragma unroll
    for (int i = 0; i < RPT; i += 2) {
        size_t p = pbase + (size_t)(i >> 1) * TPB + tid;   // row pair index
        float4 v = (p < npairs) ? nt_load_f4(x + 4 * p)
                                : make_float4(0.f, 0.f, 0.f, 0.f);
        a[i]     = v.x;  b[i]     = v.y;
        a[i + 1] = v.z;  b[i + 1] = v.w;
    }

    // stage layer 0 into buf[0] (DMA); __syncthreads drains vmcnt
    #pragma unroll
    for (int c = 0; c < CHUNKS; ++c)
        gl2lds16(tabg + c * TPB + tid, &buf[0][c * TPB + wbase]);
    __syncthreads();

    int cur = 0;
    for (int l = 0; l < NL; ++l) {
        // issue next-layer DMA into the other half (in flight during gather)
        if (l + 1 < NL) {
            const float4* __restrict__ src = tabg + (size_t)(l + 1) * NCELLS;
            #pragma unroll
            for (int c = 0; c < CHUNKS; ++c)
                gl2lds16(src + c * TPB + tid, &buf[cur ^ 1][c * TPB + wbase]);
        }

        // gather-compute current layer from buf[cur] (f32 lerp, 3 fmaf)
        #pragma unroll
        for (int i = 0; i < RPT; ++i) {
            float t  = fmaf(a[i], SCALE, OFFSET);
            float tc = __builtin_amdgcn_fmed3f(t, 0.0f, (float)(NCELLS - 1));
            float tf = truncf(tc);               // == (float)idx, 1 op
            int idx  = (int)tf;
            float f  = t - tf;                   // out-of-range -> extrapolate
            float4 nd = buf[cur][idx];
            float sh = fmaf(f, nd.z, nd.x);
            float sc = fmaf(f, nd.w, nd.y);
            float nb = fmaf(b[i], sc, sh);
            b[i] = a[i];
            a[i] = nb;
        }

        __syncthreads();   // waits vmcnt(0) + lgkmcnt(0), then barrier
        cur ^= 1;
    }

    #pragma unroll
    for (int i = 0; i < RPT; i += 2) {
        size_t p = pbase + (size_t)(i >> 1) * TPB + tid;
        if (p < npairs)
            nt_store_f4(out + 4 * p,
                        make_float4(a[i], b[i], a[i + 1], b[i + 1]));
    }
}

// ---------------- fallback: direct fp32 (ws too small) ---------------------
__global__ __launch_bounds__(256, 2) void flow_fp32_kernel(
    const float* __restrict__ x,
    const float* __restrict__ W1,
    const float* __restrict__ b1,
    const float* __restrict__ W2,
    const float* __restrict__ b2,
    const float* __restrict__ W3,
    const float* __restrict__ b3,
    float* __restrict__ out,
    int nrows)
{
    int row = blockIdx.x * blockDim.x + threadIdx.x;
    if (row >= nrows) return;

    float2 z = reinterpret_cast<const float2*>(x)[row];
    float a = z.x;
    float b = z.y;

    for (int l = 0; l < NL; ++l) {
        const float* __restrict__ w1 = W1 + l * HID;
        const float* __restrict__ c1 = b1 + l * HID;
        const float* __restrict__ w2 = W2 + l * HID * HID;
        const float* __restrict__ c2 = b2 + l * HID;
        const float* __restrict__ w3 = W3 + l * 2 * HID;
        const float* __restrict__ c3 = b3 + l * 2;

        float h1[HID];
        #pragma unroll
        for (int k = 0; k < HID; ++k) {
            float v = fmaxf(fmaf(a, w1[k], c1[k]), 0.0f);
            asm volatile("" : "+v"(v));
            h1[k] = v;
        }

        float o0 = c3[0];
        float o1 = c3[1];

        #pragma unroll 2
        for (int j = 0; j < HID; ++j) {
            const float* __restrict__ w2row = w2 + j * HID;
            float acc0 = c2[j];
            float acc1 = 0.0f;
            #pragma unroll
            for (int k = 0; k < HID; k += 2) {
                acc0 = fmaf(h1[k],     w2row[k],     acc0);
                acc1 = fmaf(h1[k + 1], w2row[k + 1], acc1);
            }
            float h = fmaxf(acc0 + acc1, 0.0f);
            o0 = fmaf(h, w3[j], o0);
            o1 = fmaf(h, w3[HID + j], o1);
        }

        float nb = fmaf(b, __expf(o1), o0);
        b = a;
        a = nb;
    }

    reinterpret_cast<float2*>(out)[row] = make_float2(a, b);
}

extern "C" void kernel_launch(void* const* d_in, const int* in_sizes, int n_in,
                              void* d_out, int out_size, void* d_ws, size_t ws_size,
                              hipStream_t stream)
{
    const float* x  = (const float*)d_in[0];
    const float* W1 = (const float*)d_in[1];
    const float* b1 = (const float*)d_in[2];
    const float* W2 = (const float*)d_in[3];
    const float* b2 = (const float*)d_in[4];
    const float* W3 = (const float*)d_in[5];
    const float* b3 = (const float*)d_in[6];
    float* out = (float*)d_out;

    int nrows = in_sizes[0] / 2;

    if (ws_size >= TAB_BYTES && (nrows & 1) == 0) {
        float4* tab = (float4*)d_ws;
        dim3 bgrid((NCELLS + GN - 1) / GN, NL);
        build_cells_kernel<<<bgrid, 1024, 0, stream>>>(W1, b1, W2, b2, W3, b3, tab);
        int grid = (nrows + ROWS_PER_BLOCK - 1) / ROWS_PER_BLOCK;
        flow_lds_kernel<<<grid, TPB, 0, stream>>>(x, tab, out, nrows);
    } else {
        int grid = (nrows + 255) / 256;
        flow_fp32_kernel<<<grid, 256, 0, stream>>>(x, W1, b1, W2, b2, W3, b3, out, nrows);
    }
}